// Round 3
// baseline (853.170 us; speedup 1.0000x reference)
//
#include <hip/hip_runtime.h>

#define B_SZ 16
#define L_SZ 1024
#define D_SZ 256
#define KW   16

typedef float f32x4 __attribute__((ext_vector_type(4)));
typedef short bf16x8 __attribute__((ext_vector_type(8)));
typedef unsigned int u32x4 __attribute__((ext_vector_type(4)));
typedef unsigned int u32x2 __attribute__((ext_vector_type(2)));

__device__ __forceinline__ unsigned short f2bf(float f) {
    union { float f; unsigned int i; } v; v.f = f;
    unsigned int r = v.i + 0x7fffu + ((v.i >> 16) & 1u);
    return (unsigned short)(r >> 16);
}
__device__ __forceinline__ float fast_sigmoid(float x) {
    float e = __builtin_amdgcn_exp2f(-1.44269504f * x);
    return __builtin_amdgcn_rcpf(1.0f + e);
}
__device__ __forceinline__ float fast_tanh(float x) {
    float e = __builtin_amdgcn_exp2f(-2.88539008f * x);
    return (1.0f - e) * __builtin_amdgcn_rcpf(1.0f + e);
}
__device__ __forceinline__ f32x4 zero4() { f32x4 v; v[0]=0.f; v[1]=0.f; v[2]=0.f; v[3]=0.f; return v; }

// ---------------------------------------------------------------------------
// prep: repack W_ih / W_hh (fp32 [768][256]) into per-wave contiguous bf16
// streams: dst[((((wid*3+g)*8+ks)*4+kg)*16+colg)*8+j] = W[g*256+wid*16+colg][ks*32+kg*8+j]
// so a wave's (g,ks) fragment is one contiguous 1KB line (lane*8 elements).
// ---------------------------------------------------------------------------
__global__ void prep_kernel(const float* __restrict__ wih,
                            const float* __restrict__ whh,
                            unsigned short* __restrict__ wpkih,
                            unsigned short* __restrict__ wpkhh) {
    const int NW = 768 * 256;  // 196608
    for (int i = blockIdx.x * blockDim.x + threadIdx.x; i < 2 * NW;
         i += gridDim.x * blockDim.x) {
        const float* W = (i < NW) ? wih : whh;
        unsigned short* dst = (i < NW) ? wpkih : wpkhh;
        int t = (i < NW) ? i : (i - NW);
        int j = t & 7;
        int q = t >> 3;
        int colg = q & 15; q >>= 4;
        int kg = q & 3;    q >>= 2;
        int ks = q & 7;    q >>= 3;
        int g = q % 3;
        int wid = q / 3;
        int src = (g * 256 + wid * 16 + colg) * 256 + ks * 32 + kg * 8 + j;
        dst[t] = f2bf(W[src]);
    }
}

// ---------------------------------------------------------------------------
// fused local-GRU: 256 blocks (b,l-tile of 64) x 1024 threads (16 waves).
// Wave wid owns h-dims [wid*16, wid*16+16) across all 3 gates.
// Per step: GEMM_ih (A = sliding x-window rows from LDS) and GEMM_hh
// (A = h tile from LDS, bf16, double-buffered) accumulate into fp32 regs;
// r,z share accumulators (i+h summed), n keeps i_n / h_n separate.
// ---------------------------------------------------------------------------
__global__ __launch_bounds__(1024, 4) void rnn_fused(
    const float* __restrict__ x,               // [B][L][256] fp32
    const unsigned short* __restrict__ wpkih,  // packed bf16
    const unsigned short* __restrict__ wpkhh,  // packed bf16
    const float* __restrict__ bih,             // [768]
    const float* __restrict__ bhh,             // [768]
    float* __restrict__ out) {                 // [B*L][256] fp32
    __shared__ unsigned short xwin[80 * 256];   // 40KB, rows l0-15..l0+64
    __shared__ unsigned short hb[2][64 * 256];  // 64KB h double buffer
    const int tid = threadIdx.x;
    const int wid = tid >> 6, lane = tid & 63;
    const int b = blockIdx.x >> 4;
    const int l0 = (blockIdx.x & 15) << 6;
    const int colg = lane & 15;
    const int kg = (lane >> 4) & 3;
    const int dcol = wid * 16 + colg;

    // stage x window: read fp32, convert to bf16, store swizzled.
    // 80 rows x 1024B fp32 = 5120 16B-chunks; each -> 8B bf16 in LDS.
    for (int c = tid; c < 5120; c += 1024) {
        int row = c >> 6;                 // 0..79
        int f0 = (c & 63) * 4;            // first float in row
        int gl = l0 - (KW - 1) + row;     // global l index
        u32x2 pk;
        if (gl >= 0 && gl < L_SZ) {
            f32x4 v = *(const f32x4*)(x + ((size_t)(b * L_SZ + gl)) * 256 + f0);
            pk[0] = (unsigned int)f2bf(v[0]) | ((unsigned int)f2bf(v[1]) << 16);
            pk[1] = (unsigned int)f2bf(v[2]) | ((unsigned int)f2bf(v[3]) << 16);
        } else {
            pk[0] = 0u; pk[1] = 0u;
        }
        int colb = f0 * 2;                // byte offset within 512B bf16 row
        *(u32x2*)((char*)xwin + row * 512 + (colb ^ ((row & 7) << 4))) = pk;
    }

    const float brz0 = bih[dcol] + bhh[dcol];
    const float brz1 = bih[256 + dcol] + bhh[256 + dcol];
    const float bin  = bih[512 + dcol];
    const float bhn  = bhh[512 + dcol];

    const unsigned short* wih_base = wpkih + (size_t)wid * 12288;
    const unsigned short* whh_base = wpkhh + (size_t)wid * 12288;

    f32x4 hst[4];
#pragma unroll
    for (int mt = 0; mt < 4; mt++) hst[mt] = zero4();

    __syncthreads();

#pragma unroll 1
    for (int k = 0; k < KW; k++) {
        f32x4 arz0[4], arz1[4], ain[4], ahn[4];
#pragma unroll
        for (int mt = 0; mt < 4; mt++) {
            arz0[mt] = zero4(); arz1[mt] = zero4();
            ain[mt]  = zero4(); ahn[mt]  = zero4();
        }

        // ---- GEMM_ih: A = xwin rows k..k+63 (sliding) ----
#pragma unroll
        for (int ks = 0; ks < 8; ks++) {
            bf16x8 w0 = *(const bf16x8*)(wih_base + (0 * 8 + ks) * 512 + lane * 8);
            bf16x8 w1 = *(const bf16x8*)(wih_base + (1 * 8 + ks) * 512 + lane * 8);
            bf16x8 w2 = *(const bf16x8*)(wih_base + (2 * 8 + ks) * 512 + lane * 8);
            const int kcol = ks * 64 + kg * 16;
#pragma unroll
            for (int mt = 0; mt < 4; mt++) {
                int row = k + mt * 16 + colg;
                bf16x8 a = *(const bf16x8*)((const char*)xwin + row * 512 +
                                            (kcol ^ ((row & 7) << 4)));
                arz0[mt] = __builtin_amdgcn_mfma_f32_16x16x32_bf16(a, w0, arz0[mt], 0, 0, 0);
                arz1[mt] = __builtin_amdgcn_mfma_f32_16x16x32_bf16(a, w1, arz1[mt], 0, 0, 0);
                ain[mt]  = __builtin_amdgcn_mfma_f32_16x16x32_bf16(a, w2, ain[mt], 0, 0, 0);
            }
        }

        // ---- GEMM_hh: A = h tile (skip at k=0, h==0) ----
        if (k > 0) {
            const unsigned short* hcur = hb[k & 1];
#pragma unroll
            for (int ks = 0; ks < 8; ks++) {
                bf16x8 w0 = *(const bf16x8*)(whh_base + (0 * 8 + ks) * 512 + lane * 8);
                bf16x8 w1 = *(const bf16x8*)(whh_base + (1 * 8 + ks) * 512 + lane * 8);
                bf16x8 w2 = *(const bf16x8*)(whh_base + (2 * 8 + ks) * 512 + lane * 8);
                const int kcol = ks * 64 + kg * 16;
#pragma unroll
                for (int mt = 0; mt < 4; mt++) {
                    int row = mt * 16 + colg;
                    bf16x8 a = *(const bf16x8*)((const char*)hcur + row * 512 +
                                                (kcol ^ ((row & 7) << 4)));
                    arz0[mt] = __builtin_amdgcn_mfma_f32_16x16x32_bf16(a, w0, arz0[mt], 0, 0, 0);
                    arz1[mt] = __builtin_amdgcn_mfma_f32_16x16x32_bf16(a, w1, arz1[mt], 0, 0, 0);
                    ahn[mt]  = __builtin_amdgcn_mfma_f32_16x16x32_bf16(a, w2, ahn[mt], 0, 0, 0);
                }
            }
        }

        // ---- gates + h update + bf16 h write (swizzled) ----
        unsigned short* hnxt = hb[(k & 1) ^ 1];
#pragma unroll
        for (int mt = 0; mt < 4; mt++) {
#pragma unroll
            for (int rr = 0; rr < 4; rr++) {
                float r = fast_sigmoid(arz0[mt][rr] + brz0);
                float z = fast_sigmoid(arz1[mt][rr] + brz1);
                float n = fast_tanh(ain[mt][rr] + bin + r * (ahn[mt][rr] + bhn));
                float h = hst[mt][rr];
                float hnew = n + z * (h - n);
                hst[mt][rr] = hnew;
                int row = mt * 16 + kg * 4 + rr;
                *(unsigned short*)((char*)hnxt + row * 512 +
                                   ((dcol * 2) ^ ((row & 7) << 4))) = f2bf(hnew);
            }
        }
        __syncthreads();
    }

    // epilogue: final h -> out
#pragma unroll
    for (int mt = 0; mt < 4; mt++) {
#pragma unroll
        for (int rr = 0; rr < 4; rr++) {
            int row = mt * 16 + kg * 4 + rr;
            out[((size_t)(b * L_SZ + l0 + row)) * D_SZ + dcol] = hst[mt][rr];
        }
    }
}

// ---------------------------------------------------------------------------
extern "C" void kernel_launch(void* const* d_in, const int* in_sizes, int n_in,
                              void* d_out, int out_size, void* d_ws, size_t ws_size,
                              hipStream_t stream) {
    const float* x   = (const float*)d_in[0];
    const float* wih = (const float*)d_in[1];
    const float* whh = (const float*)d_in[2];
    const float* bih = (const float*)d_in[3];
    const float* bhh = (const float*)d_in[4];
    float* out = (float*)d_out;

    char* ws = (char*)d_ws;
    unsigned short* wpkih = (unsigned short*)(ws);           // 393,216 B
    unsigned short* wpkhh = (unsigned short*)(ws + 393216);  // 393,216 B

    prep_kernel<<<512, 256, 0, stream>>>(wih, whh, wpkih, wpkhh);
    rnn_fused<<<256, 1024, 0, stream>>>(x, wpkih, wpkhh, bih, bhh, out);
}

// Round 5
// 331.489 us; speedup vs baseline: 2.5738x; 2.5738x over previous
//
#include <hip/hip_runtime.h>

#define B_SZ 16
#define L_SZ 1024
#define D_SZ 256
#define KW   16

typedef float f32x4 __attribute__((ext_vector_type(4)));
typedef short bf16x8 __attribute__((ext_vector_type(8)));
typedef unsigned int u32x4 __attribute__((ext_vector_type(4)));
typedef unsigned int u32x2 __attribute__((ext_vector_type(2)));

__device__ __forceinline__ float bf2f(unsigned short u) {
    union { unsigned int i; float f; } v; v.i = ((unsigned int)u) << 16; return v.f;
}
__device__ __forceinline__ unsigned short f2bf(float f) {
    union { float f; unsigned int i; } v; v.f = f;
    unsigned int r = v.i + 0x7fffu + ((v.i >> 16) & 1u);
    return (unsigned short)(r >> 16);
}
__device__ __forceinline__ float fast_sigmoid(float x) {
    float e = __builtin_amdgcn_exp2f(-1.44269504f * x);
    return __builtin_amdgcn_rcpf(1.0f + e);
}
__device__ __forceinline__ float fast_tanh(float x) {
    float e = __builtin_amdgcn_exp2f(-2.88539008f * x);
    return (1.0f - e) * __builtin_amdgcn_rcpf(1.0f + e);
}
__device__ __forceinline__ f32x4 zero4() { f32x4 v; v[0]=0.f; v[1]=0.f; v[2]=0.f; v[3]=0.f; return v; }

// ---------------------------------------------------------------------------
// prep: repack W_ih / W_hh into per-wave contiguous bf16 streams:
// wave wid slice = 3 gates x 8 ks x 512 shorts; lane l holds
// W[g*256+wid*16+(l&15)][ks*32+(l>>4)*8+j] at dst[...+l*8+j].
// ---------------------------------------------------------------------------
__global__ void prep_kernel(const float* __restrict__ wih,
                            const float* __restrict__ whh,
                            unsigned short* __restrict__ wpkih,
                            unsigned short* __restrict__ wpkhh) {
    const int NW = 768 * 256;  // 196608
    for (int i = blockIdx.x * blockDim.x + threadIdx.x; i < 2 * NW;
         i += gridDim.x * blockDim.x) {
        const float* W = (i < NW) ? wih : whh;
        unsigned short* dst = (i < NW) ? wpkih : wpkhh;
        int t = (i < NW) ? i : (i - NW);
        int j = t & 7;
        int q = t >> 3;
        int colg = q & 15; q >>= 4;
        int kg = q & 3;    q >>= 2;
        int ks = q & 7;    q >>= 3;
        int g = q % 3;
        int wid = q / 3;
        int src = (g * 256 + wid * 16 + colg) * 256 + ks * 32 + kg * 8 + j;
        dst[t] = f2bf(W[src]);
    }
}

// ---------------------------------------------------------------------------
// v4: 256 blocks x 1024 threads (16 waves, wave owns 16 h-dims x 3 gates).
// Phase 1: stage x window (80 rows bf16, swizzled)      -> xw  (40KB)
// Phase 2: one-time gi GEMM -> gi LDS bf16 [79][768]    -> gi (118.5KB)
// Phase 3: 16-step recurrence: hh GEMM only; gates read gi from LDS;
//          h single-buffer LDS (aliases dead xw), fp32 h in registers.
// ---------------------------------------------------------------------------
#define GI_PITCH 1536
#define XW_BASE  121344             /* 79*1536 */
#define LDS_BYTES (121344 + 80*512) /* 162304 */

__global__ __launch_bounds__(1024, 1) void rnn_v4(
    const float* __restrict__ x,               // [B][L][256] fp32
    const unsigned short* __restrict__ wpkih,  // packed bf16
    const unsigned short* __restrict__ wpkhh,  // packed bf16
    const float* __restrict__ bih,             // [768]
    const float* __restrict__ bhh,             // [768]
    float* __restrict__ out) {                 // [B*L][256] fp32
    __shared__ u32x4 ldsv[LDS_BYTES / 16];
    char* lds = (char*)ldsv;
    char* gi = lds;                 // [79][1536B] swizzled
    char* xw = lds + XW_BASE;       // [80][512B]  swizzled
    char* hb = lds + XW_BASE;       // alias: [64][512B] swizzled (after xw dead)

    const int tid = threadIdx.x;
    const int wid = tid >> 6, lane = tid & 63;
    const int b = blockIdx.x >> 4;
    const int l0 = (blockIdx.x & 15) << 6;
    const int colg = lane & 15;
    const int kg = (lane >> 4) & 3;
    const int dcol = wid * 16 + colg;

    // ---- phase 1: stage x window ----
    for (int c = tid; c < 5120; c += 1024) {
        int row = c >> 6;                 // 0..79
        int f0 = (c & 63) * 4;
        int gl = l0 - (KW - 1) + row;
        u32x2 pk;
        if (gl >= 0 && gl < L_SZ) {
            f32x4 v = *(const f32x4*)(x + ((size_t)(b * L_SZ + gl)) * 256 + f0);
            pk[0] = (unsigned int)f2bf(v[0]) | ((unsigned int)f2bf(v[1]) << 16);
            pk[1] = (unsigned int)f2bf(v[2]) | ((unsigned int)f2bf(v[3]) << 16);
        } else {
            pk[0] = 0u; pk[1] = 0u;
        }
        *(u32x2*)(xw + row * 512 + ((f0 * 2) ^ ((row & 7) << 4))) = pk;
    }
    __syncthreads();

    // ---- phase 2: one-time gi GEMM (includes b_ih) ----
    {
        const unsigned short* wb = wpkih + (size_t)wid * 12288;
        const float bi0 = bih[dcol];
        const float bi1 = bih[256 + dcol];
        const float bi2 = bih[512 + dcol];
#pragma unroll 1
        for (int tile = 0; tile < 5; tile++) {
            f32x4 a0 = zero4(), a1 = zero4(), a2 = zero4();
#pragma unroll
            for (int ks = 0; ks < 8; ks++) {
                bf16x8 w0 = *(const bf16x8*)(wb + (0 * 8 + ks) * 512 + lane * 8);
                bf16x8 w1 = *(const bf16x8*)(wb + (1 * 8 + ks) * 512 + lane * 8);
                bf16x8 w2 = *(const bf16x8*)(wb + (2 * 8 + ks) * 512 + lane * 8);
                int row = tile * 16 + colg;
                bf16x8 a = *(const bf16x8*)(xw + row * 512 +
                                            ((ks * 64 + kg * 16) ^ ((row & 7) << 4)));
                a0 = __builtin_amdgcn_mfma_f32_16x16x32_bf16(a, w0, a0, 0, 0, 0);
                a1 = __builtin_amdgcn_mfma_f32_16x16x32_bf16(a, w1, a1, 0, 0, 0);
                a2 = __builtin_amdgcn_mfma_f32_16x16x32_bf16(a, w2, a2, 0, 0, 0);
            }
#pragma unroll
            for (int rr = 0; rr < 4; rr++) {
                int row = tile * 16 + kg * 4 + rr;
                if (row < 79) {
                    int sw = (row & 7) << 4;
                    char* gr = gi + row * GI_PITCH;
                    *(unsigned short*)(gr + ((dcol * 2) ^ sw)) = f2bf(a0[rr] + bi0);
                    *(unsigned short*)(gr + ((512 + dcol * 2) ^ sw)) = f2bf(a1[rr] + bi1);
                    *(unsigned short*)(gr + ((1024 + dcol * 2) ^ sw)) = f2bf(a2[rr] + bi2);
                }
            }
        }
    }
    __syncthreads();

    // ---- phase 3: recurrence ----
    const unsigned short* wb = wpkhh + (size_t)wid * 12288;
    const float bz0 = bhh[dcol];
    const float bz1 = bhh[256 + dcol];
    const float bhn = bhh[512 + dcol];

    f32x4 hst[4];
#pragma unroll
    for (int mt = 0; mt < 4; mt++) hst[mt] = zero4();

#pragma unroll 1
    for (int k = 0; k < KW; k++) {
        f32x4 arz0[4], arz1[4], ahn[4];
#pragma unroll
        for (int mt = 0; mt < 4; mt++) {
            arz0[mt] = zero4(); arz1[mt] = zero4(); ahn[mt] = zero4();
        }

        if (k > 0) {
#pragma unroll
            for (int ks = 0; ks < 8; ks++) {
                bf16x8 w0 = *(const bf16x8*)(wb + (0 * 8 + ks) * 512 + lane * 8);
                bf16x8 w1 = *(const bf16x8*)(wb + (1 * 8 + ks) * 512 + lane * 8);
                bf16x8 w2 = *(const bf16x8*)(wb + (2 * 8 + ks) * 512 + lane * 8);
                const int kcol = ks * 64 + kg * 16;
#pragma unroll
                for (int mt = 0; mt < 4; mt++) {
                    int row = mt * 16 + colg;
                    bf16x8 a = *(const bf16x8*)(hb + row * 512 +
                                                (kcol ^ ((row & 7) << 4)));
                    arz0[mt] = __builtin_amdgcn_mfma_f32_16x16x32_bf16(a, w0, arz0[mt], 0, 0, 0);
                    arz1[mt] = __builtin_amdgcn_mfma_f32_16x16x32_bf16(a, w1, arz1[mt], 0, 0, 0);
                    ahn[mt]  = __builtin_amdgcn_mfma_f32_16x16x32_bf16(a, w2, ahn[mt], 0, 0, 0);
                }
            }
        }
        __syncthreads();  // all hb reads done before overwrite

#pragma unroll
        for (int mt = 0; mt < 4; mt++) {
#pragma unroll
            for (int rr = 0; rr < 4; rr++) {
                int row = mt * 16 + kg * 4 + rr;
                int xrow = k + row;
                int sw = (xrow & 7) << 4;
                const char* gr = gi + xrow * GI_PITCH;
                float ir  = bf2f(*(const unsigned short*)(gr + ((dcol * 2) ^ sw)));
                float iz  = bf2f(*(const unsigned short*)(gr + ((512 + dcol * 2) ^ sw)));
                float in_ = bf2f(*(const unsigned short*)(gr + ((1024 + dcol * 2) ^ sw)));
                float r = fast_sigmoid(ir + arz0[mt][rr] + bz0);
                float z = fast_sigmoid(iz + arz1[mt][rr] + bz1);
                float n = fast_tanh(in_ + r * (ahn[mt][rr] + bhn));
                float h = hst[mt][rr];
                float hnew = n + z * (h - n);
                hst[mt][rr] = hnew;
                *(unsigned short*)(hb + row * 512 +
                                   ((dcol * 2) ^ ((row & 7) << 4))) = f2bf(hnew);
            }
        }
        __syncthreads();  // hb writes done before next step's reads
    }

    // ---- epilogue: final h -> out ----
#pragma unroll
    for (int mt = 0; mt < 4; mt++) {
#pragma unroll
        for (int rr = 0; rr < 4; rr++) {
            int row = mt * 16 + kg * 4 + rr;
            out[((size_t)(b * L_SZ + l0 + row)) * D_SZ + dcol] = hst[mt][rr];
        }
    }
}

// ---------------------------------------------------------------------------
extern "C" void kernel_launch(void* const* d_in, const int* in_sizes, int n_in,
                              void* d_out, int out_size, void* d_ws, size_t ws_size,
                              hipStream_t stream) {
    const float* x   = (const float*)d_in[0];
    const float* wih = (const float*)d_in[1];
    const float* whh = (const float*)d_in[2];
    const float* bih = (const float*)d_in[3];
    const float* bhh = (const float*)d_in[4];
    float* out = (float*)d_out;

    char* ws = (char*)d_ws;
    unsigned short* wpkih = (unsigned short*)(ws);           // 393,216 B
    unsigned short* wpkhh = (unsigned short*)(ws + 393216);  // 393,216 B

    prep_kernel<<<512, 256, 0, stream>>>(wih, whh, wpkih, wpkhh);
    rnn_v4<<<256, 1024, 0, stream>>>(x, wpkih, wpkhh, bih, bhh, out);
}

// Round 6
// 330.307 us; speedup vs baseline: 2.5830x; 1.0036x over previous
//
#include <hip/hip_runtime.h>

#define B_SZ 16
#define L_SZ 1024
#define D_SZ 256
#define KW   16

typedef float f32x4 __attribute__((ext_vector_type(4)));
typedef short bf16x8 __attribute__((ext_vector_type(8)));
typedef unsigned int u32x4 __attribute__((ext_vector_type(4)));
typedef unsigned int u32x2 __attribute__((ext_vector_type(2)));

__device__ __forceinline__ float bf2f(unsigned short u) {
    union { unsigned int i; float f; } v; v.i = ((unsigned int)u) << 16; return v.f;
}
__device__ __forceinline__ unsigned short f2bf(float f) {
    union { float f; unsigned int i; } v; v.f = f;
    unsigned int r = v.i + 0x7fffu + ((v.i >> 16) & 1u);
    return (unsigned short)(r >> 16);
}
__device__ __forceinline__ float fast_sigmoid(float x) {
    float e = __builtin_amdgcn_exp2f(-1.44269504f * x);
    return __builtin_amdgcn_rcpf(1.0f + e);
}
__device__ __forceinline__ float fast_tanh(float x) {
    float e = __builtin_amdgcn_exp2f(-2.88539008f * x);
    return (1.0f - e) * __builtin_amdgcn_rcpf(1.0f + e);
}
__device__ __forceinline__ f32x4 zero4() { f32x4 v; v[0]=0.f; v[1]=0.f; v[2]=0.f; v[3]=0.f; return v; }

// ---------------------------------------------------------------------------
// prep: repack W_ih / W_hh into per-wave contiguous bf16 streams:
// wave wid slice = 3 gates x 8 ks x 512 shorts; lane l holds
// W[g*256+wid*16+(l&15)][ks*32+(l>>4)*8+j] at dst[...+l*8+j].
// ---------------------------------------------------------------------------
__global__ void prep_kernel(const float* __restrict__ wih,
                            const float* __restrict__ whh,
                            unsigned short* __restrict__ wpkih,
                            unsigned short* __restrict__ wpkhh) {
    const int NW = 768 * 256;  // 196608
    for (int i = blockIdx.x * blockDim.x + threadIdx.x; i < 2 * NW;
         i += gridDim.x * blockDim.x) {
        const float* W = (i < NW) ? wih : whh;
        unsigned short* dst = (i < NW) ? wpkih : wpkhh;
        int t = (i < NW) ? i : (i - NW);
        int j = t & 7;
        int q = t >> 3;
        int colg = q & 15; q >>= 4;
        int kg = q & 3;    q >>= 2;
        int ks = q & 7;    q >>= 3;
        int g = q % 3;
        int wid = q / 3;
        int src = (g * 256 + wid * 16 + colg) * 256 + ks * 32 + kg * 8 + j;
        dst[t] = f2bf(W[src]);
    }
}

// ---------------------------------------------------------------------------
// v5 = v4 structure + pinned 4 waves/EU so regalloc may use 128 VGPRs
// (R5's allocator chose 64 -> catastrophic scratch spill).
// Phase 1: stage x window (80 rows bf16, swizzled)      -> xw  (40KB)
// Phase 2: one-time gi GEMM -> gi LDS bf16 [79][768]    -> gi (118.5KB)
// Phase 3: 16-step recurrence: hh GEMM only; gates read gi from LDS;
//          h single-buffer LDS (aliases dead xw), fp32 h in registers.
// ---------------------------------------------------------------------------
#define GI_PITCH 1536
#define XW_BASE  121344             /* 79*1536 */
#define LDS_BYTES (121344 + 80*512) /* 162304 */

__global__ __launch_bounds__(1024)
__attribute__((amdgpu_waves_per_eu(4, 4)))
void rnn_v5(
    const float* __restrict__ x,               // [B][L][256] fp32
    const unsigned short* __restrict__ wpkih,  // packed bf16
    const unsigned short* __restrict__ wpkhh,  // packed bf16
    const float* __restrict__ bih,             // [768]
    const float* __restrict__ bhh,             // [768]
    float* __restrict__ out) {                 // [B*L][256] fp32
    __shared__ u32x4 ldsv[LDS_BYTES / 16];
    char* lds = (char*)ldsv;
    char* gi = lds;                 // [79][1536B] swizzled
    char* xw = lds + XW_BASE;       // [80][512B]  swizzled
    char* hb = lds + XW_BASE;       // alias: [64][512B] swizzled (after xw dead)

    const int tid = threadIdx.x;
    const int wid = tid >> 6, lane = tid & 63;
    const int b = blockIdx.x >> 4;
    const int l0 = (blockIdx.x & 15) << 6;
    const int colg = lane & 15;
    const int kg = (lane >> 4) & 3;
    const int dcol = wid * 16 + colg;

    // ---- phase 1: stage x window ----
    for (int c = tid; c < 5120; c += 1024) {
        int row = c >> 6;                 // 0..79
        int f0 = (c & 63) * 4;
        int gl = l0 - (KW - 1) + row;
        u32x2 pk;
        if (gl >= 0 && gl < L_SZ) {
            f32x4 v = *(const f32x4*)(x + ((size_t)(b * L_SZ + gl)) * 256 + f0);
            pk[0] = (unsigned int)f2bf(v[0]) | ((unsigned int)f2bf(v[1]) << 16);
            pk[1] = (unsigned int)f2bf(v[2]) | ((unsigned int)f2bf(v[3]) << 16);
        } else {
            pk[0] = 0u; pk[1] = 0u;
        }
        *(u32x2*)(xw + row * 512 + ((f0 * 2) ^ ((row & 7) << 4))) = pk;
    }
    __syncthreads();

    // ---- phase 2: one-time gi GEMM (includes b_ih) ----
    {
        const unsigned short* wb = wpkih + (size_t)wid * 12288;
        const float bi0 = bih[dcol];
        const float bi1 = bih[256 + dcol];
        const float bi2 = bih[512 + dcol];
#pragma unroll 1
        for (int tile = 0; tile < 5; tile++) {
            f32x4 a0 = zero4(), a1 = zero4(), a2 = zero4();
#pragma unroll
            for (int ks = 0; ks < 8; ks++) {
                bf16x8 w0 = *(const bf16x8*)(wb + (0 * 8 + ks) * 512 + lane * 8);
                bf16x8 w1 = *(const bf16x8*)(wb + (1 * 8 + ks) * 512 + lane * 8);
                bf16x8 w2 = *(const bf16x8*)(wb + (2 * 8 + ks) * 512 + lane * 8);
                int row = tile * 16 + colg;
                bf16x8 a = *(const bf16x8*)(xw + row * 512 +
                                            ((ks * 64 + kg * 16) ^ ((row & 7) << 4)));
                a0 = __builtin_amdgcn_mfma_f32_16x16x32_bf16(a, w0, a0, 0, 0, 0);
                a1 = __builtin_amdgcn_mfma_f32_16x16x32_bf16(a, w1, a1, 0, 0, 0);
                a2 = __builtin_amdgcn_mfma_f32_16x16x32_bf16(a, w2, a2, 0, 0, 0);
            }
#pragma unroll
            for (int rr = 0; rr < 4; rr++) {
                int row = tile * 16 + kg * 4 + rr;
                if (row < 79) {
                    int sw = (row & 7) << 4;
                    char* gr = gi + row * GI_PITCH;
                    *(unsigned short*)(gr + ((dcol * 2) ^ sw)) = f2bf(a0[rr] + bi0);
                    *(unsigned short*)(gr + ((512 + dcol * 2) ^ sw)) = f2bf(a1[rr] + bi1);
                    *(unsigned short*)(gr + ((1024 + dcol * 2) ^ sw)) = f2bf(a2[rr] + bi2);
                }
            }
        }
    }
    __syncthreads();

    // ---- phase 3: recurrence ----
    const unsigned short* wb = wpkhh + (size_t)wid * 12288;
    const float bz0 = bhh[dcol];
    const float bz1 = bhh[256 + dcol];
    const float bhn = bhh[512 + dcol];

    f32x4 hst[4];
#pragma unroll
    for (int mt = 0; mt < 4; mt++) hst[mt] = zero4();

#pragma unroll 1
    for (int k = 0; k < KW; k++) {
        f32x4 arz0[4], arz1[4], ahn[4];
#pragma unroll
        for (int mt = 0; mt < 4; mt++) {
            arz0[mt] = zero4(); arz1[mt] = zero4(); ahn[mt] = zero4();
        }

        if (k > 0) {
#pragma unroll
            for (int ks = 0; ks < 8; ks++) {
                bf16x8 w0 = *(const bf16x8*)(wb + (0 * 8 + ks) * 512 + lane * 8);
                bf16x8 w1 = *(const bf16x8*)(wb + (1 * 8 + ks) * 512 + lane * 8);
                bf16x8 w2 = *(const bf16x8*)(wb + (2 * 8 + ks) * 512 + lane * 8);
                const int kcol = ks * 64 + kg * 16;
#pragma unroll
                for (int mt = 0; mt < 4; mt++) {
                    int row = mt * 16 + colg;
                    bf16x8 a = *(const bf16x8*)(hb + row * 512 +
                                                (kcol ^ ((row & 7) << 4)));
                    arz0[mt] = __builtin_amdgcn_mfma_f32_16x16x32_bf16(a, w0, arz0[mt], 0, 0, 0);
                    arz1[mt] = __builtin_amdgcn_mfma_f32_16x16x32_bf16(a, w1, arz1[mt], 0, 0, 0);
                    ahn[mt]  = __builtin_amdgcn_mfma_f32_16x16x32_bf16(a, w2, ahn[mt], 0, 0, 0);
                }
            }
        }
        __syncthreads();  // all hb reads done before overwrite

#pragma unroll
        for (int mt = 0; mt < 4; mt++) {
#pragma unroll
            for (int rr = 0; rr < 4; rr++) {
                int row = mt * 16 + kg * 4 + rr;
                int xrow = k + row;
                int sw = (xrow & 7) << 4;
                const char* gr = gi + xrow * GI_PITCH;
                float ir  = bf2f(*(const unsigned short*)(gr + ((dcol * 2) ^ sw)));
                float iz  = bf2f(*(const unsigned short*)(gr + ((512 + dcol * 2) ^ sw)));
                float in_ = bf2f(*(const unsigned short*)(gr + ((1024 + dcol * 2) ^ sw)));
                float r = fast_sigmoid(ir + arz0[mt][rr] + bz0);
                float z = fast_sigmoid(iz + arz1[mt][rr] + bz1);
                float n = fast_tanh(in_ + r * (ahn[mt][rr] + bhn));
                float h = hst[mt][rr];
                float hnew = n + z * (h - n);
                hst[mt][rr] = hnew;
                *(unsigned short*)(hb + row * 512 +
                                   ((dcol * 2) ^ ((row & 7) << 4))) = f2bf(hnew);
            }
        }
        __syncthreads();  // hb writes done before next step's reads
    }

    // ---- epilogue: final h -> out ----
#pragma unroll
    for (int mt = 0; mt < 4; mt++) {
#pragma unroll
        for (int rr = 0; rr < 4; rr++) {
            int row = mt * 16 + kg * 4 + rr;
            out[((size_t)(b * L_SZ + l0 + row)) * D_SZ + dcol] = hst[mt][rr];
        }
    }
}

// ---------------------------------------------------------------------------
extern "C" void kernel_launch(void* const* d_in, const int* in_sizes, int n_in,
                              void* d_out, int out_size, void* d_ws, size_t ws_size,
                              hipStream_t stream) {
    const float* x   = (const float*)d_in[0];
    const float* wih = (const float*)d_in[1];
    const float* whh = (const float*)d_in[2];
    const float* bih = (const float*)d_in[3];
    const float* bhh = (const float*)d_in[4];
    float* out = (float*)d_out;

    char* ws = (char*)d_ws;
    unsigned short* wpkih = (unsigned short*)(ws);           // 393,216 B
    unsigned short* wpkhh = (unsigned short*)(ws + 393216);  // 393,216 B

    prep_kernel<<<512, 256, 0, stream>>>(wih, whh, wpkih, wpkhh);
    rnn_v5<<<256, 1024, 0, stream>>>(x, wpkih, wpkhh, bih, bhh, out);
}